// Round 3
// baseline (236.758 us; speedup 1.0000x reference)
//
#include <hip/hip_runtime.h>
#include <stdint.h>

#define NX (8192*512)   // elements of one (B*N, E) matrix
#define NW (512*512)    // elements of one weight matrix

typedef __bf16 bf16x8 __attribute__((ext_vector_type(8)));
typedef float  f32x4  __attribute__((ext_vector_type(4)));

__device__ __forceinline__ unsigned short f2bf(float f){
  unsigned u = __builtin_bit_cast(unsigned, f);
  u += 0x7FFFu + ((u >> 16) & 1u);   // RNE
  return (unsigned short)(u >> 16);
}

__device__ __forceinline__ f32x4 mfma16(bf16x8 a, bf16x8 b, f32x4 c){
  return __builtin_amdgcn_mfma_f32_16x16x32_bf16(a, b, c, 0, 0, 0);
}

__device__ __forceinline__ void gload_lds16(const void* g, void* l){
  __builtin_amdgcn_global_load_lds((const __attribute__((address_space(1))) void*)g,
                                   (__attribute__((address_space(3))) void*)l, 16, 0, 0);
}

// Drain outstanding global_load_lds before a publishing barrier. The builtin is
// vmcnt-tracked; do NOT rely on __syncthreads() to drain vmcnt for it.
__device__ __forceinline__ void drain_vm(){
  asm volatile("s_waitcnt vmcnt(0)" ::: "memory");
}

// ---------------- fp32 -> bf16 conversion of X (q,k,v) and weights ----------------
__global__ void convert_all(const float* __restrict__ q, const float* __restrict__ k,
                            const float* __restrict__ v, const float* __restrict__ wq,
                            const float* __restrict__ wk, const float* __restrict__ wv,
                            const float* __restrict__ wo, unsigned short* __restrict__ dst)
{
  const long total4 = (3L*NX + 4L*NW) / 4;
  for (long i = (long)blockIdx.x*blockDim.x + threadIdx.x; i < total4; i += (long)gridDim.x*blockDim.x){
    long e = i*4;
    const float* src; long off;
    if (e < NX)            { src = q;  off = e; }
    else if (e < 2L*NX)    { src = k;  off = e - NX; }
    else if (e < 3L*NX)    { src = v;  off = e - 2L*NX; }
    else {
      long w = e - 3L*NX; int wi = (int)(w / NW); off = w - (long)wi*NW;
      src = (wi==0) ? wq : (wi==1) ? wk : (wi==2) ? wv : wo;
    }
    float4 f = *(const float4*)(src + off);
    ushort4 o; o.x=f2bf(f.x); o.y=f2bf(f.y); o.z=f2bf(f.z); o.w=f2bf(f.w);
    *(ushort4*)(dst + e) = o;
  }
}

// ---------------- bf16 GEMM: C[m][n] = sum_k A[m][k]*B[n][k] (+bias) ----------------
// mode 0: bf16 out, (acc+bias)*scale, row-major [m][512]
// mode 1: bf16 out transposed to Vt[b*8+h][d][2048]  (V projection)
// mode 2: fp32 out + bias, row-major (final projection -> d_out)
struct GArg {
  const unsigned short* A;
  const unsigned short* B;
  const float* bias;
  void* C;
  float scale;
  int mode;
};

__global__ __launch_bounds__(256) void gemm_bt(GArg g0, GArg g1, GArg g2)
{
  GArg g = (blockIdx.z==0) ? g0 : (blockIdx.z==1) ? g1 : g2;
  __shared__ __attribute__((aligned(16))) unsigned char lds[65536];
  const int tid  = threadIdx.x;
  const int lane = tid & 63;
  const int wid  = tid >> 6;
  const int wr = wid >> 1, wc = wid & 1;
  const int m0 = blockIdx.y * 128;
  const int n0 = blockIdx.x * 128;

  f32x4 acc[4][4];
  #pragma unroll
  for (int s=0;s<4;s++)
    #pragma unroll
    for (int t=0;t<4;t++) acc[s][t] = (f32x4){0.f,0.f,0.f,0.f};

  auto stage = [&](int kt, int buf){
    int Lb = tid*16;
    #pragma unroll
    for (int i=0;i<4;i++){
      int L = Lb + i*4096;
      int row = L >> 7;
      int innerS = (L & 127) ^ ((row & 7) << 4);   // pre-swizzled source (T2)
      gload_lds16(g.A + (size_t)(m0+row)*512 + kt*64 + (innerS>>1), lds + buf*16384 + L);
    }
    #pragma unroll
    for (int i=0;i<4;i++){
      int L = Lb + i*4096;
      int row = L >> 7;
      int innerS = (L & 127) ^ ((row & 7) << 4);
      gload_lds16(g.B + (size_t)(n0+row)*512 + kt*64 + (innerS>>1), lds + 32768 + buf*16384 + L);
    }
  };

  stage(0, 0);
  drain_vm();
  __syncthreads();

  for (int kt=0; kt<8; kt++){
    int cur = kt & 1;
    if (kt < 7) stage(kt+1, cur^1);
    const unsigned char* LA = lds + cur*16384;
    const unsigned char* LB = lds + 32768 + cur*16384;
    #pragma unroll
    for (int ks=0; ks<2; ks++){
      bf16x8 af[4], bfr[4];
      #pragma unroll
      for (int s=0;s<4;s++){
        int row = wr*64 + s*16 + (lane & 15);
        int inner = (ks*32 + (lane>>4)*8)*2;
        af[s] = *(const bf16x8*)(LA + row*128 + (inner ^ ((row&7)<<4)));
      }
      #pragma unroll
      for (int t=0;t<4;t++){
        int row = wc*64 + t*16 + (lane & 15);
        int inner = (ks*32 + (lane>>4)*8)*2;
        bfr[t] = *(const bf16x8*)(LB + row*128 + (inner ^ ((row&7)<<4)));
      }
      #pragma unroll
      for (int s=0;s<4;s++)
        #pragma unroll
        for (int t=0;t<4;t++)
          acc[s][t] = mfma16(af[s], bfr[t], acc[s][t]);
    }
    drain_vm();          // publish next tile's global_load_lds before the barrier
    __syncthreads();
  }

  if (g.mode == 2){
    float* C = (float*)g.C;
    #pragma unroll
    for (int t=0;t<4;t++){
      int col = n0 + wc*64 + t*16 + (lane&15);
      float bv = g.bias[col];
      #pragma unroll
      for (int s=0;s<4;s++){
        #pragma unroll
        for (int r=0;r<4;r++){
          int row = m0 + wr*64 + s*16 + (lane>>4)*4 + r;
          C[(size_t)row*512 + col] = acc[s][t][r] + bv;
        }
      }
    }
  } else if (g.mode == 0){
    unsigned short* C = (unsigned short*)g.C;
    #pragma unroll
    for (int t=0;t<4;t++){
      int col = n0 + wc*64 + t*16 + (lane&15);
      float bv = g.bias[col];
      #pragma unroll
      for (int s=0;s<4;s++){
        #pragma unroll
        for (int r=0;r<4;r++){
          int row = m0 + wr*64 + s*16 + (lane>>4)*4 + r;
          C[(size_t)row*512 + col] = f2bf((acc[s][t][r] + bv) * g.scale);
        }
      }
    }
  } else {
    // transposed epilogue: C tile -> LDS [col][136] -> Vt[b*8+h][d][2048]
    __syncthreads();
    unsigned short* T = (unsigned short*)lds;
    #pragma unroll
    for (int s=0;s<4;s++){
      #pragma unroll
      for (int t=0;t<4;t++){
        int col  = wc*64 + t*16 + (lane&15);
        int rowb = wr*64 + s*16 + (lane>>4)*4;
        float bv = g.bias[n0+col];
        ushort4 pk;
        pk.x = f2bf(acc[s][t][0] + bv);
        pk.y = f2bf(acc[s][t][1] + bv);
        pk.z = f2bf(acc[s][t][2] + bv);
        pk.w = f2bf(acc[s][t][3] + bv);
        *(ushort4*)(T + col*136 + rowb) = pk;
      }
    }
    __syncthreads();
    unsigned short* Vt = (unsigned short*)g.C;
    int col = tid >> 1, half = tid & 1;
    int gcol = n0 + col;
    int hh = gcol >> 6, d = gcol & 63;
    int b = m0 >> 11, ms = m0 & 2047;
    unsigned short* dst = Vt + (((size_t)(b*8+hh)*64 + d)*2048 + ms + half*64);
    const unsigned short* srcT = T + col*136 + half*64;
    // int4 = 16 B = 8 shorts, matching the j*8 stride
    #pragma unroll
    for (int j=0;j<8;j++)
      *(int4*)(dst + j*8) = *(const int4*)(srcT + j*8);
  }
}

// ---------------- flash attention ----------------
// Qs: [B][N][E] bf16 (pre-scaled by 1/8), Kb: [B][N][E] bf16, Vt: [B*H][64][2048] bf16
// AO: [B][N][E] bf16
__global__ __launch_bounds__(256) void attn_kernel(
    const unsigned short* __restrict__ Qs,
    const unsigned short* __restrict__ Kb,
    const unsigned short* __restrict__ Vt,
    unsigned short* __restrict__ AO)
{
  __shared__ __attribute__((aligned(16))) unsigned char lds[28672];
  const int tid = threadIdx.x, lane = tid & 63, wid = tid >> 6;
  const int bh = blockIdx.y;
  const int b = bh >> 3, h = bh & 7;
  const int q0 = blockIdx.x*128 + wid*32;

  // Q fragments direct from global (A-operand layout)
  bf16x8 qf[2][2];
  #pragma unroll
  for (int s=0;s<2;s++)
    #pragma unroll
    for (int c=0;c<2;c++)
      qf[s][c] = *(const bf16x8*)(Qs + (size_t)(b*2048 + q0 + s*16 + (lane&15))*512
                                     + h*64 + c*32 + (lane>>4)*8);

  f32x4 o[2][4];
  float mrow[2][4], lrow[2][4];
  #pragma unroll
  for (int s=0;s<2;s++){
    #pragma unroll
    for (int dt=0;dt<4;dt++) o[s][dt] = (f32x4){0.f,0.f,0.f,0.f};
    #pragma unroll
    for (int r=0;r<4;r++){ mrow[s][r] = -1e30f; lrow[s][r] = 0.f; }
  }

  // prologue: stage tile 0 (K swizzled via global_load_lds, Vt via regs)
  {
    int L = tid*16; int row = L>>7; int innerS = (L&127) ^ ((row&7)<<4);
    gload_lds16(Kb + (size_t)(b*2048 + row)*512 + h*64 + (innerS>>1), lds + L);
    int d = tid>>2, part = tid&3;
    int4 v0 = *(const int4*)(Vt + ((size_t)bh*64 + d)*2048 + part*8);
    *(int4*)(lds + 8192 + (d*40 + part*8)*2) = v0;
  }
  drain_vm();
  __syncthreads();

  for (int t=0; t<64; t++){
    int cur = t & 1;
    int4 vnext;
    int dstage = tid>>2, pstage = tid&3;
    if (t < 63){
      int L = tid*16; int row = L>>7; int innerS = (L&127) ^ ((row&7)<<4);
      gload_lds16(Kb + (size_t)(b*2048 + (t+1)*32 + row)*512 + h*64 + (innerS>>1),
                  lds + (cur^1)*4096 + L);
      vnext = *(const int4*)(Vt + ((size_t)bh*64 + dstage)*2048 + (t+1)*32 + pstage*8);
    }

    const unsigned char* KL = lds + cur*4096;
    const unsigned char* VL = lds + 8192 + cur*5120;

    // K^T B-fragments (shared across both strips)
    bf16x8 kbf[2][2];
    #pragma unroll
    for (int cb=0; cb<2; cb++)
      #pragma unroll
      for (int c=0; c<2; c++){
        int kvr = cb*16 + (lane&15);
        int inner = (c*32 + (lane>>4)*8)*2;
        kbf[cb][c] = *(const bf16x8*)(KL + kvr*128 + (inner ^ ((kvr&7)<<4)));
      }

    #pragma unroll
    for (int s=0;s<2;s++){
      f32x4 S[2];
      #pragma unroll
      for (int cb=0;cb<2;cb++){
        f32x4 z = (f32x4){0.f,0.f,0.f,0.f};
        z = mfma16(qf[s][0], kbf[cb][0], z);
        z = mfma16(qf[s][1], kbf[cb][1], z);
        S[cb] = z;
      }
      // online softmax (rows live in reg r, kv spread across 16 lanes x 2 frags)
      float rm[4], pr0[4], pr1[4], rs[4];
      #pragma unroll
      for (int r=0;r<4;r++) rm[r] = fmaxf(S[0][r], S[1][r]);
      #pragma unroll
      for (int m=1; m<16; m<<=1)
        #pragma unroll
        for (int r=0;r<4;r++) rm[r] = fmaxf(rm[r], __shfl_xor(rm[r], m));
      #pragma unroll
      for (int r=0;r<4;r++){
        float mn = fmaxf(mrow[s][r], rm[r]);
        float corr = exp2f((mrow[s][r]-mn)*1.44269504f);
        mrow[s][r] = mn;
        pr0[r] = exp2f((S[0][r]-mn)*1.44269504f);
        pr1[r] = exp2f((S[1][r]-mn)*1.44269504f);
        rs[r] = pr0[r] + pr1[r];
        lrow[s][r] *= corr;
        #pragma unroll
        for (int dt=0;dt<4;dt++) o[s][dt][r] *= corr;
      }
      #pragma unroll
      for (int m=1; m<16; m<<=1)
        #pragma unroll
        for (int r=0;r<4;r++) rs[r] += __shfl_xor(rs[r], m);
      #pragma unroll
      for (int r=0;r<4;r++) lrow[s][r] += rs[r];

      // P -> bf16 -> LDS [16][40] (per wave, per strip)
      unsigned short* P = (unsigned short*)(lds + 18432 + (wid*2+s)*1280);
      #pragma unroll
      for (int r=0;r<4;r++){
        int row = (lane>>4)*4 + r;
        P[row*40 + (lane&15)]      = f2bf(pr0[r]);
        P[row*40 + 16 + (lane&15)] = f2bf(pr1[r]);
      }
    }

    // PV: o[s][dt] += P(16x32) * V(32x16dt)
    bf16x8 vf[4];
    #pragma unroll
    for (int dt=0;dt<4;dt++)
      vf[dt] = *(const bf16x8*)(VL + ((dt*16 + (lane&15))*40 + (lane>>4)*8)*2);
    #pragma unroll
    for (int s=0;s<2;s++){
      const unsigned short* P = (const unsigned short*)(lds + 18432 + (wid*2+s)*1280);
      bf16x8 pf = *(const bf16x8*)(P + (lane&15)*40 + (lane>>4)*8);
      #pragma unroll
      for (int dt=0;dt<4;dt++)
        o[s][dt] = mfma16(pf, vf[dt], o[s][dt]);
    }

    if (t < 63)
      *(int4*)(lds + 8192 + (cur^1)*5120 + (dstage*40 + pstage*8)*2) = vnext;
    drain_vm();          // publish next K tile's global_load_lds before the barrier
    __syncthreads();
  }

  // epilogue: normalize and write AO [b][n][h*64+d]
  #pragma unroll
  for (int s=0;s<2;s++){
    float inv[4];
    #pragma unroll
    for (int r=0;r<4;r++) inv[r] = 1.0f / lrow[s][r];
    #pragma unroll
    for (int dt=0;dt<4;dt++){
      int col = h*64 + dt*16 + (lane&15);
      #pragma unroll
      for (int r=0;r<4;r++){
        int row = b*2048 + q0 + s*16 + (lane>>4)*4 + r;
        AO[(size_t)row*512 + col] = f2bf(o[s][dt][r] * inv[r]);
      }
    }
  }
}

extern "C" void kernel_launch(void* const* d_in, const int* in_sizes, int n_in,
                              void* d_out, int out_size, void* d_ws, size_t ws_size,
                              hipStream_t stream)
{
  const float* q  = (const float*)d_in[0];
  const float* k  = (const float*)d_in[1];
  const float* v  = (const float*)d_in[2];
  const float* Wq = (const float*)d_in[3];
  const float* bq = (const float*)d_in[4];
  const float* Wk = (const float*)d_in[5];
  const float* bk = (const float*)d_in[6];
  const float* Wv = (const float*)d_in[7];
  const float* bv = (const float*)d_in[8];
  const float* Wo = (const float*)d_in[9];
  const float* bo = (const float*)d_in[10];

  unsigned short* X   = (unsigned short*)d_ws;
  unsigned short* Xq  = X;
  unsigned short* Xk  = X + NX;
  unsigned short* Xv  = X + 2*(size_t)NX;
  unsigned short* WqB = X + 3*(size_t)NX;
  unsigned short* WkB = WqB + NW;
  unsigned short* WvB = WqB + 2*(size_t)NW;
  unsigned short* WoB = WqB + 3*(size_t)NW;
  unsigned short* QS  = WqB + 4*(size_t)NW;
  unsigned short* KB  = QS + NX;
  unsigned short* VT  = KB + NX;
  unsigned short* AO  = VT + NX;

  convert_all<<<dim3(2048), dim3(256), 0, stream>>>(q, k, v, Wq, Wk, Wv, Wo, X);

  GArg gq{Xq, WqB, bq, (void*)QS, 0.125f, 0};   // SCALE folded into Q
  GArg gk{Xk, WkB, bk, (void*)KB, 1.0f,   0};
  GArg gv{Xv, WvB, bv, (void*)VT, 1.0f,   1};   // transposed epilogue
  gemm_bt<<<dim3(4, 64, 3), dim3(256), 0, stream>>>(gq, gk, gv);

  attn_kernel<<<dim3(16, 32), dim3(256), 0, stream>>>(QS, KB, VT, AO);

  GArg go{AO, WoB, bo, d_out, 1.0f, 2};
  gemm_bt<<<dim3(4, 64, 1), dim3(256), 0, stream>>>(go, go, go);
}

// Round 4
// 161.335 us; speedup vs baseline: 1.4675x; 1.4675x over previous
//
#include <hip/hip_runtime.h>
#include <stdint.h>

#define NX (8192*512)   // elements of one (B*N, E) matrix
#define NW (512*512)    // elements of one weight matrix

typedef __bf16 bf16x8 __attribute__((ext_vector_type(8)));
typedef float  f32x4  __attribute__((ext_vector_type(4)));

__device__ __forceinline__ unsigned short f2bf(float f){
  unsigned u = __builtin_bit_cast(unsigned, f);
  u += 0x7FFFu + ((u >> 16) & 1u);   // RNE
  return (unsigned short)(u >> 16);
}

__device__ __forceinline__ f32x4 mfma16(bf16x8 a, bf16x8 b, f32x4 c){
  return __builtin_amdgcn_mfma_f32_16x16x32_bf16(a, b, c, 0, 0, 0);
}

__device__ __forceinline__ void gload_lds16(const void* g, void* l){
  __builtin_amdgcn_global_load_lds((const __attribute__((address_space(1))) void*)g,
                                   (__attribute__((address_space(3))) void*)l, 16, 0, 0);
}

// Drain outstanding global_load_lds before a publishing barrier. The builtin is
// vmcnt-tracked; do NOT rely on __syncthreads() to drain vmcnt for it.
__device__ __forceinline__ void drain_vm(){
  asm volatile("s_waitcnt vmcnt(0)" ::: "memory");
}

// ---------------- fp32 -> bf16 conversion of X (q,k,v) and weights ----------------
__global__ void convert_all(const float* __restrict__ q, const float* __restrict__ k,
                            const float* __restrict__ v, const float* __restrict__ wq,
                            const float* __restrict__ wk, const float* __restrict__ wv,
                            const float* __restrict__ wo, unsigned short* __restrict__ dst)
{
  const long total4 = (3L*NX + 4L*NW) / 4;
  for (long i = (long)blockIdx.x*blockDim.x + threadIdx.x; i < total4; i += (long)gridDim.x*blockDim.x){
    long e = i*4;
    const float* src; long off;
    if (e < NX)            { src = q;  off = e; }
    else if (e < 2L*NX)    { src = k;  off = e - NX; }
    else if (e < 3L*NX)    { src = v;  off = e - 2L*NX; }
    else {
      long w = e - 3L*NX; int wi = (int)(w / NW); off = w - (long)wi*NW;
      src = (wi==0) ? wq : (wi==1) ? wk : (wi==2) ? wv : wo;
    }
    float4 f = *(const float4*)(src + off);
    ushort4 o; o.x=f2bf(f.x); o.y=f2bf(f.y); o.z=f2bf(f.z); o.w=f2bf(f.w);
    *(ushort4*)(dst + e) = o;
  }
}

// ---------------- bf16 GEMM: C[m][n] = sum_k A[m][k]*B[n][k] (+bias) ----------------
struct GArg {
  const unsigned short* A;
  const unsigned short* B;
  const float* bias;
  void* C;
  float scale;
  int mode;
};

__global__ __launch_bounds__(256) void gemm_bt(GArg g0, GArg g1, GArg g2)
{
  GArg g = (blockIdx.z==0) ? g0 : (blockIdx.z==1) ? g1 : g2;
  __shared__ __attribute__((aligned(16))) unsigned char lds[65536];
  const int tid  = threadIdx.x;
  const int lane = tid & 63;
  const int wid  = tid >> 6;
  const int wr = wid >> 1, wc = wid & 1;
  const int m0 = blockIdx.y * 128;
  const int n0 = blockIdx.x * 128;

  f32x4 acc[4][4];
  #pragma unroll
  for (int s=0;s<4;s++)
    #pragma unroll
    for (int t=0;t<4;t++) acc[s][t] = (f32x4){0.f,0.f,0.f,0.f};

  auto stage = [&](int kt, int buf){
    int Lb = tid*16;
    #pragma unroll
    for (int i=0;i<4;i++){
      int L = Lb + i*4096;
      int row = L >> 7;
      int innerS = (L & 127) ^ ((row & 7) << 4);   // pre-swizzled source (T2)
      gload_lds16(g.A + (size_t)(m0+row)*512 + kt*64 + (innerS>>1), lds + buf*16384 + L);
    }
    #pragma unroll
    for (int i=0;i<4;i++){
      int L = Lb + i*4096;
      int row = L >> 7;
      int innerS = (L & 127) ^ ((row & 7) << 4);
      gload_lds16(g.B + (size_t)(n0+row)*512 + kt*64 + (innerS>>1), lds + 32768 + buf*16384 + L);
    }
  };

  stage(0, 0);
  drain_vm();
  __syncthreads();

  for (int kt=0; kt<8; kt++){
    int cur = kt & 1;
    if (kt < 7) stage(kt+1, cur^1);
    const unsigned char* LA = lds + cur*16384;
    const unsigned char* LB = lds + 32768 + cur*16384;
    #pragma unroll
    for (int ks=0; ks<2; ks++){
      bf16x8 af[4], bfr[4];
      #pragma unroll
      for (int s=0;s<4;s++){
        int row = wr*64 + s*16 + (lane & 15);
        int inner = (ks*32 + (lane>>4)*8)*2;
        af[s] = *(const bf16x8*)(LA + row*128 + (inner ^ ((row&7)<<4)));
      }
      #pragma unroll
      for (int t=0;t<4;t++){
        int row = wc*64 + t*16 + (lane & 15);
        int inner = (ks*32 + (lane>>4)*8)*2;
        bfr[t] = *(const bf16x8*)(LB + row*128 + (inner ^ ((row&7)<<4)));
      }
      #pragma unroll
      for (int s=0;s<4;s++)
        #pragma unroll
        for (int t=0;t<4;t++)
          acc[s][t] = mfma16(af[s], bfr[t], acc[s][t]);
    }
    drain_vm();          // publish next tile's global_load_lds before the barrier
    __syncthreads();
  }

  if (g.mode == 2){
    float* C = (float*)g.C;
    #pragma unroll
    for (int t=0;t<4;t++){
      int col = n0 + wc*64 + t*16 + (lane&15);
      float bv = g.bias[col];
      #pragma unroll
      for (int s=0;s<4;s++){
        #pragma unroll
        for (int r=0;r<4;r++){
          int row = m0 + wr*64 + s*16 + (lane>>4)*4 + r;
          C[(size_t)row*512 + col] = acc[s][t][r] + bv;
        }
      }
    }
  } else if (g.mode == 0){
    unsigned short* C = (unsigned short*)g.C;
    #pragma unroll
    for (int t=0;t<4;t++){
      int col = n0 + wc*64 + t*16 + (lane&15);
      float bv = g.bias[col];
      #pragma unroll
      for (int s=0;s<4;s++){
        #pragma unroll
        for (int r=0;r<4;r++){
          int row = m0 + wr*64 + s*16 + (lane>>4)*4 + r;
          C[(size_t)row*512 + col] = f2bf((acc[s][t][r] + bv) * g.scale);
        }
      }
    }
  } else {
    // transposed epilogue: C tile -> LDS [col][136] -> Vt[b*8+h][d][2048]
    __syncthreads();
    unsigned short* T = (unsigned short*)lds;
    #pragma unroll
    for (int s=0;s<4;s++){
      #pragma unroll
      for (int t=0;t<4;t++){
        int col  = wc*64 + t*16 + (lane&15);
        int rowb = wr*64 + s*16 + (lane>>4)*4;
        float bv = g.bias[n0+col];
        ushort4 pk;
        pk.x = f2bf(acc[s][t][0] + bv);
        pk.y = f2bf(acc[s][t][1] + bv);
        pk.z = f2bf(acc[s][t][2] + bv);
        pk.w = f2bf(acc[s][t][3] + bv);
        *(ushort4*)(T + col*136 + rowb) = pk;
      }
    }
    __syncthreads();
    unsigned short* Vt = (unsigned short*)g.C;
    int col = tid >> 1, half = tid & 1;
    int gcol = n0 + col;
    int hh = gcol >> 6, d = gcol & 63;
    int b = m0 >> 11, ms = m0 & 2047;
    unsigned short* dst = Vt + (((size_t)(b*8+hh)*64 + d)*2048 + ms + half*64);
    const unsigned short* srcT = T + col*136 + half*64;
    #pragma unroll
    for (int j=0;j<8;j++)
      *(int4*)(dst + j*8) = *(const int4*)(srcT + j*8);
  }
}

// ---------------- flash attention (swapped QK^T, in-lane softmax, defer-max) ----------------
// Qs: [B][N][E] bf16 (pre-scaled by 1/8), Kb: [B][N][E] bf16, Vt: [B*H][64][2048] bf16
// AO: [B][N][E] bf16
__global__ __launch_bounds__(256) void attn_kernel(
    const unsigned short* __restrict__ Qs,
    const unsigned short* __restrict__ Kb,
    const unsigned short* __restrict__ Vt,
    unsigned short* __restrict__ AO)
{
  // LDS layout:
  //   0..8191      K tiles dbuf [2][32 rows][128B] (XOR-swizzled reads)
  //   8192..18431  V tiles dbuf [2][64 d][80B]
  //   18432..26623 P per (wave,strip) [8][16 q][64B]   (stride 64B: bank-optimal)
  //   26624..27135 scratch [8][16 floats]              (corr / 1/l broadcast)
  __shared__ __attribute__((aligned(16))) unsigned char lds[27648];
  const int tid = threadIdx.x, lane = tid & 63, wid = tid >> 6;
  const int bh = blockIdx.y;
  const int b = bh >> 3, h = bh & 7;
  const int q0 = blockIdx.x*128 + wid*32;
  const int lq = lane & 15;     // q-column owned by this lane (softmax domain)
  const int g  = lane >> 4;     // lane group

  // Q fragments (B-operand of swapped QK^T: col=q=lq, k=d)
  bf16x8 qf[2][2];
  #pragma unroll
  for (int s=0;s<2;s++)
    #pragma unroll
    for (int c=0;c<2;c++)
      qf[s][c] = *(const bf16x8*)(Qs + (size_t)(b*2048 + q0 + s*16 + lq)*512
                                     + h*64 + c*32 + g*8);

  f32x4 o[2][4];
  float m_run[2], l_run[2];
  #pragma unroll
  for (int s=0;s<2;s++){
    #pragma unroll
    for (int dt=0;dt<4;dt++) o[s][dt] = (f32x4){0.f,0.f,0.f,0.f};
    m_run[s] = -1e30f; l_run[s] = 0.f;
  }

  // prologue: stage tile 0
  {
    int L = tid*16; int row = L>>7; int innerS = (L&127) ^ ((row&7)<<4);
    gload_lds16(Kb + (size_t)(b*2048 + row)*512 + h*64 + (innerS>>1), lds + L);
    int d = tid>>2, part = tid&3;
    int4 v0 = *(const int4*)(Vt + ((size_t)bh*64 + d)*2048 + part*8);
    *(int4*)(lds + 8192 + (d*40 + part*8)*2) = v0;
  }
  drain_vm();
  __syncthreads();

  const float LOG2E = 1.44269504f;

  for (int t=0; t<64; t++){
    int cur = t & 1;
    int4 vnext;
    int dstage = tid>>2, pstage = tid&3;
    if (t < 63){
      int L = tid*16; int row = L>>7; int innerS = (L&127) ^ ((row&7)<<4);
      gload_lds16(Kb + (size_t)(b*2048 + (t+1)*32 + row)*512 + h*64 + (innerS>>1),
                  lds + (cur^1)*4096 + L);
      vnext = *(const int4*)(Vt + ((size_t)bh*64 + dstage)*2048 + (t+1)*32 + pstage*8);
    }

    const unsigned char* KL = lds + cur*4096;
    const unsigned char* VL = lds + 8192 + cur*5120;

    // K fragments (A-operand: row=kv, k=d) — same addressing as before
    bf16x8 kbf[2][2];
    #pragma unroll
    for (int cb=0; cb<2; cb++)
      #pragma unroll
      for (int c=0; c<2; c++){
        int kvr = cb*16 + lq;
        int inner = (c*32 + g*8)*2;
        kbf[cb][c] = *(const bf16x8*)(KL + kvr*128 + (inner ^ ((kvr&7)<<4)));
      }

    // V fragments for PV (B-operand: col=d, k=kv) — shared across strips
    bf16x8 vf[4];
    #pragma unroll
    for (int dt=0;dt<4;dt++)
      vf[dt] = *(const bf16x8*)(VL + ((dt*16 + lq)*40 + g*8)*2);

    #pragma unroll
    for (int s=0;s<2;s++){
      // S^T = K · Q^T : lane owns q=lq, holds kv = cb*16 + g*4 + r in regs
      f32x4 S[2];
      #pragma unroll
      for (int cb=0;cb<2;cb++){
        f32x4 z = (f32x4){0.f,0.f,0.f,0.f};
        z = mfma16(kbf[cb][0], qf[s][0], z);
        z = mfma16(kbf[cb][1], qf[s][1], z);
        S[cb] = z;
      }

      // tile max: 7 in-reg fmax + 2 cross-group shuffles
      float mt = fmaxf(fmaxf(fmaxf(S[0][0],S[0][1]),fmaxf(S[0][2],S[0][3])),
                       fmaxf(fmaxf(S[1][0],S[1][1]),fmaxf(S[1][2],S[1][3])));
      mt = fmaxf(mt, __shfl_xor(mt, 16));
      mt = fmaxf(mt, __shfl_xor(mt, 32));

      // defer-max: rescale only when the running max grew by > 8
      if (!__all(mt <= m_run[s] + 8.0f)){
        float mn = fmaxf(m_run[s], mt);
        float corr = exp2f((m_run[s]-mn)*LOG2E);
        l_run[s] *= corr;
        m_run[s] = mn;
        float* sc = (float*)(lds + 26624 + (wid*2+s)*64);
        if (lane < 16) sc[lq] = corr;          // q-domain -> o-domain transpose
        f32x4 c4 = *(const f32x4*)(sc + g*4);
        #pragma unroll
        for (int dt=0;dt<4;dt++)
          #pragma unroll
          for (int r=0;r<4;r++) o[s][dt][r] *= c4[r];
      }

      float mc = m_run[s]*LOG2E;
      float p[2][4];
      #pragma unroll
      for (int cb=0;cb<2;cb++)
        #pragma unroll
        for (int r=0;r<4;r++)
          p[cb][r] = exp2f(S[cb][r]*LOG2E - mc);

      float rs = ((p[0][0]+p[0][1])+(p[0][2]+p[0][3]))
               + ((p[1][0]+p[1][1])+(p[1][2]+p[1][3]));
      rs += __shfl_xor(rs, 16);
      rs += __shfl_xor(rs, 32);
      l_run[s] += rs;

      // P[q][kv] bf16, stride 64B: lane writes kv = cb*16 + g*4 + {0..3}
      unsigned char* Pb = lds + 18432 + (wid*2+s)*1024;
      #pragma unroll
      for (int cb=0;cb<2;cb++){
        unsigned lo = (unsigned)f2bf(p[cb][0]) | ((unsigned)f2bf(p[cb][1])<<16);
        unsigned hi = (unsigned)f2bf(p[cb][2]) | ((unsigned)f2bf(p[cb][3])<<16);
        uint2 w; w.x = lo; w.y = hi;
        *(uint2*)(Pb + lq*64 + cb*32 + g*8) = w;
      }
    }

    // PV: o[s][dt] += P(16x32) * V(32x16dt)
    #pragma unroll
    for (int s=0;s<2;s++){
      const unsigned char* Pb = lds + 18432 + (wid*2+s)*1024;
      bf16x8 pf = *(const bf16x8*)(Pb + lq*64 + g*16);
      #pragma unroll
      for (int dt=0;dt<4;dt++)
        o[s][dt] = mfma16(pf, vf[dt], o[s][dt]);
    }

    if (t < 63)
      *(int4*)(lds + 8192 + (cur^1)*5120 + (dstage*40 + pstage*8)*2) = vnext;
    drain_vm();          // publish next K tile's global_load_lds before the barrier
    __syncthreads();
  }

  // epilogue: normalize and write AO [b][n][h*64+d]
  #pragma unroll
  for (int s=0;s<2;s++){
    float* sc = (float*)(lds + 26624 + (wid*2+s)*64);
    if (lane < 16) sc[lq] = 1.0f / l_run[s];
    f32x4 li = *(const f32x4*)(sc + g*4);
    #pragma unroll
    for (int dt=0;dt<4;dt++){
      int col = h*64 + dt*16 + lq;
      #pragma unroll
      for (int r=0;r<4;r++){
        int row = b*2048 + q0 + s*16 + g*4 + r;
        AO[(size_t)row*512 + col] = f2bf(o[s][dt][r] * li[r]);
      }
    }
  }
}

extern "C" void kernel_launch(void* const* d_in, const int* in_sizes, int n_in,
                              void* d_out, int out_size, void* d_ws, size_t ws_size,
                              hipStream_t stream)
{
  const float* q  = (const float*)d_in[0];
  const float* k  = (const float*)d_in[1];
  const float* v  = (const float*)d_in[2];
  const float* Wq = (const float*)d_in[3];
  const float* bq = (const float*)d_in[4];
  const float* Wk = (const float*)d_in[5];
  const float* bk = (const float*)d_in[6];
  const float* Wv = (const float*)d_in[7];
  const float* bv = (const float*)d_in[8];
  const float* Wo = (const float*)d_in[9];
  const float* bo = (const float*)d_in[10];

  unsigned short* X   = (unsigned short*)d_ws;
  unsigned short* Xq  = X;
  unsigned short* Xk  = X + NX;
  unsigned short* Xv  = X + 2*(size_t)NX;
  unsigned short* WqB = X + 3*(size_t)NX;
  unsigned short* WkB = WqB + NW;
  unsigned short* WvB = WqB + 2*(size_t)NW;
  unsigned short* WoB = WqB + 3*(size_t)NW;
  unsigned short* QS  = WqB + 4*(size_t)NW;
  unsigned short* KB  = QS + NX;
  unsigned short* VT  = KB + NX;
  unsigned short* AO  = VT + NX;

  convert_all<<<dim3(2048), dim3(256), 0, stream>>>(q, k, v, Wq, Wk, Wv, Wo, X);

  GArg gq{Xq, WqB, bq, (void*)QS, 0.125f, 0};   // SCALE folded into Q
  GArg gk{Xk, WkB, bk, (void*)KB, 1.0f,   0};
  GArg gv{Xv, WvB, bv, (void*)VT, 1.0f,   1};   // transposed epilogue
  gemm_bt<<<dim3(4, 64, 3), dim3(256), 0, stream>>>(gq, gk, gv);

  attn_kernel<<<dim3(16, 32), dim3(256), 0, stream>>>(QS, KB, VT, AO);

  GArg go{AO, WoB, bo, d_out, 1.0f, 2};
  gemm_bt<<<dim3(4, 64, 1), dim3(256), 0, stream>>>(go, go, go);
}

// Round 5
// 143.950 us; speedup vs baseline: 1.6447x; 1.1208x over previous
//
#include <hip/hip_runtime.h>
#include <stdint.h>

#define NX (8192*512)   // elements of one (B*N, E) matrix
#define NW (512*512)    // elements of one weight matrix

typedef __bf16 bf16x8 __attribute__((ext_vector_type(8)));
typedef float  f32x4  __attribute__((ext_vector_type(4)));

__device__ __forceinline__ unsigned short f2bf(float f){
  unsigned u = __builtin_bit_cast(unsigned, f);
  u += 0x7FFFu + ((u >> 16) & 1u);   // RNE
  return (unsigned short)(u >> 16);
}

__device__ __forceinline__ f32x4 mfma16(bf16x8 a, bf16x8 b, f32x4 c){
  return __builtin_amdgcn_mfma_f32_16x16x32_bf16(a, b, c, 0, 0, 0);
}

__device__ __forceinline__ void gload_lds16(const void* g, void* l){
  __builtin_amdgcn_global_load_lds((const __attribute__((address_space(1))) void*)g,
                                   (__attribute__((address_space(3))) void*)l, 16, 0, 0);
}

// Drain outstanding global_load_lds before a publishing barrier.
__device__ __forceinline__ void drain_vm(){
  asm volatile("s_waitcnt vmcnt(0)" ::: "memory");
}

// ---------------- fp32 -> bf16 conversion of X (q,k,v) and weights ----------------
__global__ void convert_all(const float* __restrict__ q, const float* __restrict__ k,
                            const float* __restrict__ v, const float* __restrict__ wq,
                            const float* __restrict__ wk, const float* __restrict__ wv,
                            const float* __restrict__ wo, unsigned short* __restrict__ dst)
{
  const long total4 = (3L*NX + 4L*NW) / 4;
  for (long i = (long)blockIdx.x*blockDim.x + threadIdx.x; i < total4; i += (long)gridDim.x*blockDim.x){
    long e = i*4;
    const float* src; long off;
    if (e < NX)            { src = q;  off = e; }
    else if (e < 2L*NX)    { src = k;  off = e - NX; }
    else if (e < 3L*NX)    { src = v;  off = e - 2L*NX; }
    else {
      long w = e - 3L*NX; int wi = (int)(w / NW); off = w - (long)wi*NW;
      src = (wi==0) ? wq : (wi==1) ? wk : (wi==2) ? wv : wo;
    }
    float4 f = *(const float4*)(src + off);
    ushort4 o; o.x=f2bf(f.x); o.y=f2bf(f.y); o.z=f2bf(f.z); o.w=f2bf(f.w);
    *(ushort4*)(dst + e) = o;
  }
}

// ---------------- bf16 GEMM: C[m][n] = sum_k A[m][k]*B[n][k] (+bias) ----------------
struct GArg {
  const unsigned short* A;
  const unsigned short* B;
  const float* bias;
  void* C;
  float scale;
  int mode;
};

__global__ __launch_bounds__(256) void gemm_bt(GArg g0, GArg g1, GArg g2)
{
  GArg g = (blockIdx.z==0) ? g0 : (blockIdx.z==1) ? g1 : g2;
  __shared__ __attribute__((aligned(16))) unsigned char lds[65536];
  const int tid  = threadIdx.x;
  const int lane = tid & 63;
  const int wid  = tid >> 6;
  const int wr = wid >> 1, wc = wid & 1;
  const int m0 = blockIdx.y * 128;
  const int n0 = blockIdx.x * 128;

  f32x4 acc[4][4];
  #pragma unroll
  for (int s=0;s<4;s++)
    #pragma unroll
    for (int t=0;t<4;t++) acc[s][t] = (f32x4){0.f,0.f,0.f,0.f};

  auto stage = [&](int kt, int buf){
    int Lb = tid*16;
    #pragma unroll
    for (int i=0;i<4;i++){
      int L = Lb + i*4096;
      int row = L >> 7;
      int innerS = (L & 127) ^ ((row & 7) << 4);   // pre-swizzled source (T2)
      gload_lds16(g.A + (size_t)(m0+row)*512 + kt*64 + (innerS>>1), lds + buf*16384 + L);
    }
    #pragma unroll
    for (int i=0;i<4;i++){
      int L = Lb + i*4096;
      int row = L >> 7;
      int innerS = (L & 127) ^ ((row & 7) << 4);
      gload_lds16(g.B + (size_t)(n0+row)*512 + kt*64 + (innerS>>1), lds + 32768 + buf*16384 + L);
    }
  };

  stage(0, 0);
  drain_vm();
  __syncthreads();

  for (int kt=0; kt<8; kt++){
    int cur = kt & 1;
    if (kt < 7) stage(kt+1, cur^1);
    const unsigned char* LA = lds + cur*16384;
    const unsigned char* LB = lds + 32768 + cur*16384;
    #pragma unroll
    for (int ks=0; ks<2; ks++){
      bf16x8 af[4], bfr[4];
      #pragma unroll
      for (int s=0;s<4;s++){
        int row = wr*64 + s*16 + (lane & 15);
        int inner = (ks*32 + (lane>>4)*8)*2;
        af[s] = *(const bf16x8*)(LA + row*128 + (inner ^ ((row&7)<<4)));
      }
      #pragma unroll
      for (int t=0;t<4;t++){
        int row = wc*64 + t*16 + (lane & 15);
        int inner = (ks*32 + (lane>>4)*8)*2;
        bfr[t] = *(const bf16x8*)(LB + row*128 + (inner ^ ((row&7)<<4)));
      }
      #pragma unroll
      for (int s=0;s<4;s++)
        #pragma unroll
        for (int t=0;t<4;t++)
          acc[s][t] = mfma16(af[s], bfr[t], acc[s][t]);
    }
    drain_vm();          // publish next tile's global_load_lds before the barrier
    __syncthreads();
  }

  if (g.mode == 2){
    float* C = (float*)g.C;
    #pragma unroll
    for (int t=0;t<4;t++){
      int col = n0 + wc*64 + t*16 + (lane&15);
      float bv = g.bias[col];
      #pragma unroll
      for (int s=0;s<4;s++){
        #pragma unroll
        for (int r=0;r<4;r++){
          int row = m0 + wr*64 + s*16 + (lane>>4)*4 + r;
          C[(size_t)row*512 + col] = acc[s][t][r] + bv;
        }
      }
    }
  } else if (g.mode == 0){
    unsigned short* C = (unsigned short*)g.C;
    #pragma unroll
    for (int t=0;t<4;t++){
      int col = n0 + wc*64 + t*16 + (lane&15);
      float bv = g.bias[col];
      #pragma unroll
      for (int s=0;s<4;s++){
        #pragma unroll
        for (int r=0;r<4;r++){
          int row = m0 + wr*64 + s*16 + (lane>>4)*4 + r;
          C[(size_t)row*512 + col] = f2bf((acc[s][t][r] + bv) * g.scale);
        }
      }
    }
  } else {
    // transposed epilogue: C tile -> LDS [col][136] -> Vt[b*8+h][d][2048]
    __syncthreads();
    unsigned short* T = (unsigned short*)lds;
    #pragma unroll
    for (int s=0;s<4;s++){
      #pragma unroll
      for (int t=0;t<4;t++){
        int col  = wc*64 + t*16 + (lane&15);
        int rowb = wr*64 + s*16 + (lane>>4)*4;
        float bv = g.bias[n0+col];
        ushort4 pk;
        pk.x = f2bf(acc[s][t][0] + bv);
        pk.y = f2bf(acc[s][t][1] + bv);
        pk.z = f2bf(acc[s][t][2] + bv);
        pk.w = f2bf(acc[s][t][3] + bv);
        *(ushort4*)(T + col*136 + rowb) = pk;
      }
    }
    __syncthreads();
    unsigned short* Vt = (unsigned short*)g.C;
    int col = tid >> 1, half = tid & 1;
    int gcol = n0 + col;
    int hh = gcol >> 6, d = gcol & 63;
    int b = m0 >> 11, ms = m0 & 2047;
    unsigned short* dst = Vt + (((size_t)(b*8+hh)*64 + d)*2048 + ms + half*64);
    const unsigned short* srcT = T + col*136 + half*64;
    #pragma unroll
    for (int j=0;j<8;j++)
      *(int4*)(dst + j*8) = *(const int4*)(srcT + j*8);
  }
}

// ---------------- flash attention (kv-slot permuted: P never leaves registers) ----
// kv-slot permutation sigma(kv = cb*16+g*4+r) = g*8+cb*4+r applied to BOTH P and V:
// lane's QK^T outputs p[cb][r] are directly its PV A-fragment (slot j = cb*4+r);
// V B-fragment reads V rows {g*4..+3} and {16+g*4..+3}: two b64, 2-way per phase.
// Qs: [B][N][E] bf16 (pre-scaled by 1/8), Kb: [B][N][E] bf16, Vt: [B*H][64][2048]
__global__ __launch_bounds__(256) void attn_kernel(
    const unsigned short* __restrict__ Qs,
    const unsigned short* __restrict__ Kb,
    const unsigned short* __restrict__ Vt,
    unsigned short* __restrict__ AO)
{
  // LDS: 0..8191 K dbuf [2][32 rows][128B] (XOR-swizzled)
  //      8192..18431 V dbuf [2][64 d][80B]
  //      18432..18687 scratch [4 waves][64B]
  __shared__ __attribute__((aligned(16))) unsigned char lds[18688];
  const int tid = threadIdx.x, lane = tid & 63, wid = tid >> 6;
  const int bh = blockIdx.y;
  const int b = bh >> 3, h = bh & 7;
  const int q0 = blockIdx.x*64 + wid*16;   // 16 q-rows per wave
  const int lq = lane & 15;                // q-column owned by this lane
  const int g  = lane >> 4;                // lane group

  // Q fragments (B-operand of swapped QK^T)
  bf16x8 qf[2];
  #pragma unroll
  for (int c=0;c<2;c++)
    qf[c] = *(const bf16x8*)(Qs + (size_t)(b*2048 + q0 + lq)*512 + h*64 + c*32 + g*8);

  f32x4 o[4];
  #pragma unroll
  for (int dt=0;dt<4;dt++) o[dt] = (f32x4){0.f,0.f,0.f,0.f};
  float m_run = -1e30f, l_run = 0.f;

  // prologue: stage tile 0
  {
    int L = tid*16; int row = L>>7; int innerS = (L&127) ^ ((row&7)<<4);
    gload_lds16(Kb + (size_t)(b*2048 + row)*512 + h*64 + (innerS>>1), lds + L);
    int d = tid>>2, part = tid&3;
    uint4 v0 = *(const uint4*)(Vt + ((size_t)bh*64 + d)*2048 + part*8);
    *(uint4*)(lds + 8192 + (d*40 + part*8)*2) = v0;
  }
  drain_vm();
  __syncthreads();

  const float LOG2E = 1.44269504f;

  for (int t=0; t<64; t++){
    int cur = t & 1;
    uint4 vnext;
    int dstage = tid>>2, pstage = tid&3;
    if (t < 63){
      int L = tid*16; int row = L>>7; int innerS = (L&127) ^ ((row&7)<<4);
      gload_lds16(Kb + (size_t)(b*2048 + (t+1)*32 + row)*512 + h*64 + (innerS>>1),
                  lds + (cur^1)*4096 + L);
      vnext = *(const uint4*)(Vt + ((size_t)bh*64 + dstage)*2048 + (t+1)*32 + pstage*8);
    }

    const unsigned char* KL = lds + cur*4096;
    const unsigned char* VL = lds + 8192 + cur*5120;

    // K fragments (A-operand of swapped QK^T)
    bf16x8 kbf[2][2];
    #pragma unroll
    for (int cb=0; cb<2; cb++)
      #pragma unroll
      for (int c=0; c<2; c++){
        int kvr = cb*16 + lq;
        int inner = (c*32 + g*8)*2;
        kbf[cb][c] = *(const bf16x8*)(KL + kvr*128 + (inner ^ ((kvr&7)<<4)));
      }

    // V fragments, kv-slot permuted: slots g*8+{0..7} = V rows {g*4..+3, 16+g*4..+3}
    bf16x8 vf[4];
    #pragma unroll
    for (int dt=0;dt<4;dt++){
      const unsigned char* rowp = VL + (dt*16 + lq)*80;
      uint2 lo = *(const uint2*)(rowp + g*8);
      uint2 hi = *(const uint2*)(rowp + 32 + g*8);
      uint4 allv; allv.x = lo.x; allv.y = lo.y; allv.z = hi.x; allv.w = hi.y;
      vf[dt] = __builtin_bit_cast(bf16x8, allv);
    }

    // S^T = K · Q^T : lane owns q=lq, holds kv = cb*16 + g*4 + r in regs
    f32x4 S[2];
    #pragma unroll
    for (int cb=0;cb<2;cb++){
      f32x4 z = (f32x4){0.f,0.f,0.f,0.f};
      z = mfma16(kbf[cb][0], qf[0], z);
      z = mfma16(kbf[cb][1], qf[1], z);
      S[cb] = z;
    }

    // tile max: 7 in-reg fmax + 2 cross-group shuffles
    float mt = fmaxf(fmaxf(fmaxf(S[0][0],S[0][1]),fmaxf(S[0][2],S[0][3])),
                     fmaxf(fmaxf(S[1][0],S[1][1]),fmaxf(S[1][2],S[1][3])));
    mt = fmaxf(mt, __shfl_xor(mt, 16));
    mt = fmaxf(mt, __shfl_xor(mt, 32));

    // defer-max: rescale only when the running max grew by > 8
    if (!__all(mt <= m_run + 8.0f)){
      float mn = fmaxf(m_run, mt);
      float corr = exp2f((m_run-mn)*LOG2E);
      l_run *= corr;
      m_run = mn;
      float* sc = (float*)(lds + 18432 + wid*64);
      if (lane < 16) sc[lq] = corr;          // q-domain -> o-domain transpose
      f32x4 c4 = *(const f32x4*)(sc + g*4);
      #pragma unroll
      for (int dt=0;dt<4;dt++)
        #pragma unroll
        for (int r=0;r<4;r++) o[dt][r] *= c4[r];
    }

    float mc = m_run*LOG2E;
    float p[2][4];
    #pragma unroll
    for (int cb=0;cb<2;cb++)
      #pragma unroll
      for (int r=0;r<4;r++)
        p[cb][r] = exp2f(S[cb][r]*LOG2E - mc);

    float rs = ((p[0][0]+p[0][1])+(p[0][2]+p[0][3]))
             + ((p[1][0]+p[1][1])+(p[1][2]+p[1][3]));
    rs += __shfl_xor(rs, 16);
    rs += __shfl_xor(rs, 32);
    l_run += rs;

    // P fragment directly in registers (slot j = cb*4+r)
    bf16x8 pf;
    #pragma unroll
    for (int cb=0;cb<2;cb++)
      #pragma unroll
      for (int r=0;r<4;r++)
        pf[cb*4+r] = (__bf16)p[cb][r];

    // PV
    #pragma unroll
    for (int dt=0;dt<4;dt++)
      o[dt] = mfma16(pf, vf[dt], o[dt]);

    if (t < 63)
      *(uint4*)(lds + 8192 + (cur^1)*5120 + (dstage*40 + pstage*8)*2) = vnext;
    drain_vm();          // publish next K tile's global_load_lds before the barrier
    __syncthreads();
  }

  // epilogue: normalize and write AO [b][n][h*64+d]
  {
    float* sc = (float*)(lds + 18432 + wid*64);
    if (lane < 16) sc[lq] = 1.0f / l_run;
    f32x4 li = *(const f32x4*)(sc + g*4);
    #pragma unroll
    for (int dt=0;dt<4;dt++){
      int col = h*64 + dt*16 + lq;
      #pragma unroll
      for (int r=0;r<4;r++){
        int row = b*2048 + q0 + g*4 + r;
        AO[(size_t)row*512 + col] = f2bf(o[dt][r] * li[r]);
      }
    }
  }
}

extern "C" void kernel_launch(void* const* d_in, const int* in_sizes, int n_in,
                              void* d_out, int out_size, void* d_ws, size_t ws_size,
                              hipStream_t stream)
{
  const float* q  = (const float*)d_in[0];
  const float* k  = (const float*)d_in[1];
  const float* v  = (const float*)d_in[2];
  const float* Wq = (const float*)d_in[3];
  const float* bq = (const float*)d_in[4];
  const float* Wk = (const float*)d_in[5];
  const float* bk = (const float*)d_in[6];
  const float* Wv = (const float*)d_in[7];
  const float* bv = (const float*)d_in[8];
  const float* Wo = (const float*)d_in[9];
  const float* bo = (const float*)d_in[10];

  unsigned short* X   = (unsigned short*)d_ws;
  unsigned short* Xq  = X;
  unsigned short* Xk  = X + NX;
  unsigned short* Xv  = X + 2*(size_t)NX;
  unsigned short* WqB = X + 3*(size_t)NX;
  unsigned short* WkB = WqB + NW;
  unsigned short* WvB = WqB + 2*(size_t)NW;
  unsigned short* WoB = WqB + 3*(size_t)NW;
  unsigned short* QS  = WqB + 4*(size_t)NW;
  unsigned short* KB  = QS + NX;
  unsigned short* VT  = KB + NX;
  unsigned short* AO  = VT + NX;

  convert_all<<<dim3(2048), dim3(256), 0, stream>>>(q, k, v, Wq, Wk, Wv, Wo, X);

  GArg gq{Xq, WqB, bq, (void*)QS, 0.125f, 0};   // SCALE folded into Q
  GArg gk{Xk, WkB, bk, (void*)KB, 1.0f,   0};
  GArg gv{Xv, WvB, bv, (void*)VT, 1.0f,   1};   // transposed epilogue
  gemm_bt<<<dim3(4, 64, 3), dim3(256), 0, stream>>>(gq, gk, gv);

  attn_kernel<<<dim3(32, 32), dim3(256), 0, stream>>>(QS, KB, VT, AO);

  GArg go{AO, WoB, bo, d_out, 1.0f, 2};
  gemm_bt<<<dim3(4, 64, 1), dim3(256), 0, stream>>>(go, go, go);
}